// Round 2
// baseline (4998.381 us; speedup 1.0000x reference)
//
#include <hip/hip_runtime.h>

// SDCN forward on MI355X — Round 2: split-bf16 (hi+lo) MFMA GEMMs.
// C = A@B with A≈Ah+Al, B≈Bh+Bl computed as AhBh + AlBh + AhBl via
// mfma_f32_16x16x32_bf16 (fp32 accumulate) => ~1e-5 relative error.
// AE decoder is dead code (outputs don't depend on it) — skipped.
// Fallback: fp32 tiled GEMM path if ws_size < required (~795 MB).

#define NROWS   10000
#define ADJ_KP  10016          // 10000 padded to multiple of 32
#define SIGMA_F 0.3f

typedef short s8v __attribute__((ext_vector_type(8)));   // 8 bf16 (4 VGPRs)
typedef float f4v __attribute__((ext_vector_type(4)));   // MFMA accum

// epilogue/output flags
#define F_RELU   1
#define F_BIAS   2
#define F_OUTF32 4
#define F_OUTRM  8
#define F_OUTT   16
#define F_MIX    32

// ---------------------------------------------------------------------------
// bf16 helpers (bit ops, RNE)
// ---------------------------------------------------------------------------
__device__ __forceinline__ unsigned short f2bf(float f) {
    union { float f; unsigned int u; } c; c.f = f;
    unsigned int r = c.u + 0x7fffu + ((c.u >> 16) & 1u);
    return (unsigned short)(r >> 16);
}
__device__ __forceinline__ float bf2f(unsigned short h) {
    union { unsigned int u; float f; } c; c.u = ((unsigned int)h) << 16;
    return c.f;
}
__device__ __forceinline__ void split2(float f, unsigned short& h, unsigned short& l) {
    h = f2bf(f);
    l = f2bf(f - bf2f(h));   // residual; f - bf2f(h) is exact in fp32
}

// ---------------------------------------------------------------------------
// Split-bf16 MFMA GEMM.  C[M,N] = A[M,Kp] @ B[Kp,N] (logical), where
//  - A given as row-major split pair (Ah,Al), stride Kp
//  - B given TRANSPOSED as split pair (Bh,Bl): Bt[n][k], stride Kp
// 128x128 tile, BK=32, 256 threads = 4 waves (2x2), 4x4 16x16 frags per wave.
// LDS XOR slot-swizzle (slot ^= (row>>1)&3) => conflict-free b128 read/write.
// A rows are clamped to M-1 (OOB output rows are never stored); B "rows"
// (= cols of C) beyond N must exist in the allocation (garbage ok, unread).
// ---------------------------------------------------------------------------
__global__ __launch_bounds__(256)
void gemm_split_kernel(const unsigned short* __restrict__ Ah, const unsigned short* __restrict__ Al,
                       const unsigned short* __restrict__ Bh, const unsigned short* __restrict__ Bl,
                       int M, int N, int Kp, int gx,
                       const float* __restrict__ bias, int flags,
                       float* __restrict__ Cf,
                       unsigned short* __restrict__ Ch, unsigned short* __restrict__ Cl, int ldct,
                       const unsigned short* __restrict__ Mixh, const unsigned short* __restrict__ Mixl)
{
    __shared__ s8v lds8[2048];            // 32 KB: tiles Ah|Al|Bh|Bl, 8 KB each
    char* ldsb = (char*)lds8;

    const int tid  = threadIdx.x;
    const int lane = tid & 63;
    const int wid  = tid >> 6;            // wave 0..3
    const int wr   = wid >> 1;            // wave row of 2x2
    const int wc   = wid & 1;             // wave col

    // bijective XCD-chunked block swizzle (m204 form)
    const int nwg = gridDim.x;
    const int q8 = nwg >> 3, r8 = nwg & 7;
    const int xcd = blockIdx.x & 7, sidx = blockIdx.x >> 3;
    const int wg = (xcd < r8 ? xcd * (q8 + 1) : r8 * (q8 + 1) + (xcd - r8) * q8) + sidx;
    const int bx = wg % gx, by = wg / gx;
    const long row0 = (long)by * 128;
    const long col0 = (long)bx * 128;

    // ---- staging: wave `wid` stages tile `wid` (Ah,Al,Bh,Bl) ----
    const unsigned short* sbase = (wid == 0) ? Ah : (wid == 1) ? Al : (wid == 2) ? Bh : Bl;
    const int rloc  = lane >> 2;          // 0..15
    const int lslot = lane & 3;           // logical 16B slot (k-offset lslot*8)
    long goff[8]; int pbyte[8];
    #pragma unroll
    for (int c = 0; c < 8; ++c) {
        int r = c * 16 + rloc;            // tile row 0..127
        long gr;
        if (wid < 2) { long t = row0 + r; gr = (t < M) ? t : (long)(M - 1); }   // clamp A rows
        else         { gr = col0 + r; }                                          // B rows padded alloc
        goff[c]  = gr * (long)Kp + lslot * 8;
        int ps   = lslot ^ ((r >> 1) & 3);                                       // XOR swizzle
        pbyte[c] = wid * 8192 + r * 64 + ps * 16;
    }

    f4v acc[4][4];
    #pragma unroll
    for (int i = 0; i < 4; ++i)
        #pragma unroll
        for (int j = 0; j < 4; ++j) acc[i][j] = (f4v){0.f, 0.f, 0.f, 0.f};

    const int fr  = lane & 15;
    const int c16 = lane >> 4;

    s8v stg[8];
    #pragma unroll
    for (int c = 0; c < 8; ++c) stg[c] = *(const s8v*)(sbase + goff[c]);

    const int nsteps = Kp >> 5;
    for (int s = 0; s < nsteps; ++s) {
        #pragma unroll
        for (int c = 0; c < 8; ++c) *(s8v*)(ldsb + pbyte[c]) = stg[c];
        __syncthreads();
        if (s + 1 < nsteps) {             // prefetch next K-step during MFMA
            long k0 = (long)(s + 1) << 5;
            #pragma unroll
            for (int c = 0; c < 8; ++c) stg[c] = *(const s8v*)(sbase + goff[c] + k0);
        }
        s8v ahf[4], alf[4];
        #pragma unroll
        for (int i = 0; i < 4; ++i) {
            int R  = wr * 64 + i * 16 + fr;
            int bo = R * 64 + ((c16 ^ ((R >> 1) & 3)) << 4);
            ahf[i] = *(const s8v*)(ldsb + bo);
            alf[i] = *(const s8v*)(ldsb + 8192 + bo);
        }
        #pragma unroll
        for (int j = 0; j < 4; ++j) {
            int Cc = wc * 64 + j * 16 + fr;
            int bo = Cc * 64 + ((c16 ^ ((Cc >> 1) & 3)) << 4);
            s8v bhf = *(const s8v*)(ldsb + 16384 + bo);
            s8v blf = *(const s8v*)(ldsb + 24576 + bo);
            #pragma unroll
            for (int i = 0; i < 4; ++i) {
                acc[i][j] = __builtin_amdgcn_mfma_f32_16x16x32_bf16(ahf[i], bhf, acc[i][j], 0, 0, 0);
                acc[i][j] = __builtin_amdgcn_mfma_f32_16x16x32_bf16(alf[i], bhf, acc[i][j], 0, 0, 0);
                acc[i][j] = __builtin_amdgcn_mfma_f32_16x16x32_bf16(ahf[i], blf, acc[i][j], 0, 0, 0);
            }
        }
        __syncthreads();
    }

    // ---- epilogue: C/D layout (m89): col = lane&15, row = (lane>>4)*4 + reg ----
    #pragma unroll
    for (int i = 0; i < 4; ++i) {
        #pragma unroll
        for (int rg = 0; rg < 4; ++rg) {
            long gm = row0 + wr * 64 + i * 16 + c16 * 4 + rg;
            if (gm >= M) continue;
            #pragma unroll
            for (int j = 0; j < 4; ++j) {
                long gn = col0 + wc * 64 + j * 16 + fr;
                if (gn >= N) continue;
                float v = acc[i][j][rg];
                if (flags & F_BIAS) v += bias[gn];
                if (flags & F_RELU) v = fmaxf(v, 0.f);
                if (flags & F_MIX)
                    v = (1.f - SIGMA_F) * v +
                        SIGMA_F * (bf2f(Mixh[gm * (long)N + gn]) + bf2f(Mixl[gm * (long)N + gn]));
                if (flags & F_OUTF32) Cf[gm * (long)N + gn] = v;
                if (flags & (F_OUTRM | F_OUTT)) {
                    unsigned short h, l; split2(v, h, l);
                    if (flags & F_OUTRM) { Ch[gm * (long)N + gn] = h; Cl[gm * (long)N + gn] = l; }
                    else                 { Ch[gn * (long)ldct + gm] = h; Cl[gn * (long)ldct + gm] = l; }
                }
            }
        }
    }
}

// ---------------------------------------------------------------------------
// converts / small fused ops
// ---------------------------------------------------------------------------
__global__ void split_rm_kernel(const float* __restrict__ src, unsigned short* __restrict__ h,
                                unsigned short* __restrict__ l, long M, long K, long Kp)
{
    long q = Kp >> 2;
    long total = M * q;
    for (long t = (long)blockIdx.x * blockDim.x + threadIdx.x; t < total;
         t += (long)gridDim.x * blockDim.x) {
        long row = t / q;
        long k4  = (t - row * q) << 2;
        unsigned short hh[4], ll[4];
        if (k4 < K) {
            const float* p = src + row * K + k4;
            #pragma unroll
            for (int e = 0; e < 4; ++e) split2(p[e], hh[e], ll[e]);
        } else {
            #pragma unroll
            for (int e = 0; e < 4; ++e) { hh[e] = 0; ll[e] = 0; }
        }
        long o = row * Kp + k4;
        *(ushort4*)(h + o) = make_ushort4(hh[0], hh[1], hh[2], hh[3]);
        *(ushort4*)(l + o) = make_ushort4(ll[0], ll[1], ll[2], ll[3]);
    }
}

// W[K][N] fp32 -> transposed split Wt[n][k]
__global__ void split_wt_kernel(const float* __restrict__ wsrc, unsigned short* __restrict__ th,
                                unsigned short* __restrict__ tl, int K, int N)
{
    int idx = blockIdx.x * blockDim.x + threadIdx.x;
    if (idx >= N * K) return;
    int n = idx / K, k = idx - n * K;
    unsigned short h, l;
    split2(wsrc[(long)k * N + n], h, l);
    th[(long)n * K + k] = h;
    tl[(long)n * K + k] = l;
}

// zero the K-pad columns (k in [10000,10016)) of the transposed t-slot
__global__ void zpad_kernel(unsigned short* __restrict__ th, unsigned short* __restrict__ tl)
{
    int idx = blockIdx.x * blockDim.x + threadIdx.x;
    if (idx >= 2048 * 16) return;
    int n = idx >> 4, k = 10000 + (idx & 15);
    th[(long)n * ADJ_KP + k] = 0;
    tl[(long)n * ADJ_KP + k] = 0;
}

// r4 = relu(h4) -> split;  m5 = 0.7*r4 + 0.3*z -> split
__global__ void relu_mix_split_kernel(const float* __restrict__ h4, const float* __restrict__ z,
                                      unsigned short* __restrict__ r4h, unsigned short* __restrict__ r4l,
                                      unsigned short* __restrict__ m5h, unsigned short* __restrict__ m5l,
                                      int n)
{
    int i = blockIdx.x * blockDim.x + threadIdx.x;
    if (i >= n) return;
    float r = fmaxf(h4[i], 0.f);
    unsigned short h, l;
    split2(r, h, l); r4h[i] = h; r4l[i] = l;
    float m = (1.f - SIGMA_F) * r + SIGMA_F * z[i];
    split2(m, h, l); m5h[i] = h; m5l[i] = l;
}

__global__ void softmax16_kernel(const float* __restrict__ hv, float* __restrict__ out, int M)
{
    int r = blockIdx.x * blockDim.x + threadIdx.x;
    if (r >= M) return;
    float v[16];
    float mx = -1e30f;
    #pragma unroll
    for (int j = 0; j < 16; ++j) { v[j] = hv[r * 16 + j]; mx = fmaxf(mx, v[j]); }
    float s = 0.f;
    #pragma unroll
    for (int j = 0; j < 16; ++j) { v[j] = __expf(v[j] - mx); s += v[j]; }
    float inv = 1.f / s;
    #pragma unroll
    for (int j = 0; j < 16; ++j) out[r * 16 + j] = v[j] * inv;
}

__global__ void qdist_kernel(const float* __restrict__ h4, const float* __restrict__ cluster,
                             float* __restrict__ q, int M)
{
    int r = blockIdx.x * blockDim.x + threadIdx.x;
    if (r >= M) return;
    float d2[16];
    #pragma unroll
    for (int k = 0; k < 16; ++k) d2[k] = 0.f;
    for (int d = 0; d < 64; ++d) {
        float hv = h4[r * 64 + d];
        #pragma unroll
        for (int k = 0; k < 16; ++k) {
            float df = hv - cluster[k * 64 + d];
            d2[k] = fmaf(df, df, d2[k]);
        }
    }
    float s = 0.f, qq[16];
    #pragma unroll
    for (int k = 0; k < 16; ++k) { qq[k] = 1.f / (1.f + d2[k]); s += qq[k]; }
    float inv = 1.f / s;
    #pragma unroll
    for (int k = 0; k < 16; ++k) q[r * 16 + k] = qq[k] * inv;
}

// ---------------------------------------------------------------------------
// fp32 fallback GEMM (round-1 path, used only if ws_size too small)
// ---------------------------------------------------------------------------
template<int BM, int BN, int BK, int TM, int TN>
__global__ __launch_bounds__((BM/TM)*(BN/TN))
void sgemm_kernel(const float* __restrict__ A, const float* __restrict__ B,
                  const float* __restrict__ bias, float* __restrict__ C,
                  int M, int N, int K, int act)
{
    constexpr int THREADS = (BM/TM)*(BN/TN);
    __shared__ float As[BK][BM+4];
    __shared__ float Bs[BK][BN+4];
    const int  tid  = threadIdx.x;
    const long row0 = (long)blockIdx.y * BM;
    const long col0 = (long)blockIdx.x * BN;
    const int  tcol = (tid % (BN/TN)) * TN;
    const int  trow = (tid / (BN/TN)) * TM;
    float acc[TM][TN];
    #pragma unroll
    for (int i = 0; i < TM; ++i)
        #pragma unroll
        for (int j = 0; j < TN; ++j) acc[i][j] = 0.f;
    constexpr int A_ITER = (BM*BK/4) / THREADS;
    constexpr int B_ITER = (BK*BN/4) / THREADS;
    for (int k0 = 0; k0 < K; k0 += BK) {
        #pragma unroll
        for (int it = 0; it < A_ITER; ++it) {
            int lin = (tid + it*THREADS) * 4;
            int r  = lin / BK;
            int kk = lin % BK;
            float4 v = {0.f, 0.f, 0.f, 0.f};
            if (row0 + r < M)
                v = *reinterpret_cast<const float4*>(A + (row0 + r) * (long)K + k0 + kk);
            As[kk+0][r] = v.x; As[kk+1][r] = v.y; As[kk+2][r] = v.z; As[kk+3][r] = v.w;
        }
        #pragma unroll
        for (int it = 0; it < B_ITER; ++it) {
            int lin = (tid + it*THREADS) * 4;
            int kk = lin / BN;
            int c  = lin % BN;
            float4 v = {0.f, 0.f, 0.f, 0.f};
            if (col0 + c < N)
                v = *reinterpret_cast<const float4*>(B + (long)(k0 + kk) * N + col0 + c);
            *reinterpret_cast<float4*>(&Bs[kk][c]) = v;
        }
        __syncthreads();
        #pragma unroll
        for (int kk = 0; kk < BK; ++kk) {
            float a[TM], b[TN];
            #pragma unroll
            for (int i = 0; i < TM; ++i) a[i] = As[kk][trow + i];
            #pragma unroll
            for (int j = 0; j < TN; ++j) b[j] = Bs[kk][tcol + j];
            #pragma unroll
            for (int i = 0; i < TM; ++i)
                #pragma unroll
                for (int j = 0; j < TN; ++j)
                    acc[i][j] = fmaf(a[i], b[j], acc[i][j]);
        }
        __syncthreads();
    }
    #pragma unroll
    for (int i = 0; i < TM; ++i) {
        long r = row0 + trow + i;
        if (r >= M) continue;
        #pragma unroll
        for (int j = 0; j < TN; ++j) {
            long c = col0 + tcol + j;
            if (c >= N) continue;
            float v = acc[i][j];
            if (bias) v += bias[c];
            if (act)  v = fmaxf(v, 0.f);
            C[r * N + c] = v;
        }
    }
}

__global__ void mix_kernel(const float* __restrict__ a, const float* __restrict__ b,
                           float* __restrict__ out, int n)
{
    int i = blockIdx.x * blockDim.x + threadIdx.x;
    if (i < n) out[i] = (1.f - SIGMA_F) * a[i] + SIGMA_F * b[i];
}
__global__ void relu_mix_kernel(const float* __restrict__ h4, const float* __restrict__ z,
                                float* __restrict__ r4, float* __restrict__ m4, int n)
{
    int i = blockIdx.x * blockDim.x + threadIdx.x;
    if (i < n) {
        float r = fmaxf(h4[i], 0.f);
        r4[i] = r;
        m4[i] = (1.f - SIGMA_F) * r + SIGMA_F * z[i];
    }
}

// ---------------------------------------------------------------------------
static inline void gemm_split(const unsigned short* Ah, const unsigned short* Al,
                              const unsigned short* Bh, const unsigned short* Bl,
                              int M, int N, int Kp, const float* bias, int flags,
                              float* Cf, unsigned short* Ch, unsigned short* Cl, int ldct,
                              const unsigned short* Mixh, const unsigned short* Mixl,
                              hipStream_t s)
{
    int gx = (N + 127) / 128, gy = (M + 127) / 128;
    gemm_split_kernel<<<gx * gy, 256, 0, s>>>(Ah, Al, Bh, Bl, M, N, Kp, gx,
                                              bias, flags, Cf, Ch, Cl, ldct, Mixh, Mixl);
}
static inline void gemm128(const float* A, const float* B, const float* bias, float* C,
                           int M, int N, int K, int act, hipStream_t s)
{
    dim3 grid((N + 127) / 128, (M + 127) / 128);
    sgemm_kernel<128,128,16,8,8><<<grid, 256, 0, s>>>(A, B, bias, C, M, N, K, act);
}
static inline void gemm64(const float* A, const float* B, const float* bias, float* C,
                          int M, int N, int K, int act, hipStream_t s)
{
    dim3 grid((N + 63) / 64, (M + 63) / 64);
    sgemm_kernel<64,64,16,4,4><<<grid, 256, 0, s>>>(A, B, bias, C, M, N, K, act);
}

extern "C" void kernel_launch(void* const* d_in, const int* in_sizes, int n_in,
                              void* d_out, int out_size, void* d_ws, size_t ws_size,
                              hipStream_t stream)
{
    const float* x    = (const float*)d_in[0];   // [10000,1024]
    const float* adj  = (const float*)d_in[1];   // [10000,10000]
    const float* e1w  = (const float*)d_in[2];   const float* e1b = (const float*)d_in[3];
    const float* e2w  = (const float*)d_in[4];   const float* e2b = (const float*)d_in[5];
    const float* e3w  = (const float*)d_in[6];   const float* e3b = (const float*)d_in[7];
    const float* zw   = (const float*)d_in[8];   const float* zb  = (const float*)d_in[9];
    // d_in[10..17]: AE decoder params — dead code
    const float* g1   = (const float*)d_in[18];
    const float* g2   = (const float*)d_in[19];
    const float* g3   = (const float*)d_in[20];
    const float* g4   = (const float*)d_in[21];
    const float* g5   = (const float*)d_in[22];
    const float* fcw  = (const float*)d_in[23];  const float* fcb = (const float*)d_in[24];
    const float* cl   = (const float*)d_in[25];  // [16,64]

    float* out   = (float*)d_out;
    float* x_bar = out;                               // [10000,1024]
    float* qout  = out + (size_t)NROWS * 1024;        // [10000,16]
    float* pred  = qout + (size_t)NROWS * 16;         // [10000,16]
    float* zout  = pred + (size_t)NROWS * 16;         // [10000,64]

    const int EL = 256;
    typedef unsigned short us;

    // ---------- split-bf16 workspace layout ----------
    size_t cur = 0;
    auto take = [&](size_t b) { size_t o = cur; cur += (b + 255) & ~(size_t)255; return o; };
    const size_t o_adjh  = take((size_t)NROWS * ADJ_KP * 2);
    const size_t o_adjl  = take((size_t)NROWS * ADJ_KP * 2);
    const size_t o_xh    = take((size_t)NROWS * 1024 * 2);
    const size_t o_xl    = take((size_t)NROWS * 1024 * 2);
    const size_t o_t1h   = take((size_t)NROWS * 512 * 2);   // tra1 split
    const size_t o_t1l   = take((size_t)NROWS * 512 * 2);
    const size_t o_t2h   = take((size_t)NROWS * 512 * 2);
    const size_t o_t2l   = take((size_t)NROWS * 512 * 2);
    const size_t o_t3h   = take((size_t)NROWS * 2048 * 2);
    const size_t o_t3l   = take((size_t)NROWS * 2048 * 2);
    const size_t o_tsh   = take((size_t)2048 * ADJ_KP * 2); // transposed t-slot
    const size_t o_tsl   = take((size_t)2048 * ADJ_KP * 2);
    const size_t o_m2h   = take((size_t)NROWS * 512 * 2);
    const size_t o_m2l   = take((size_t)NROWS * 512 * 2);
    const size_t o_m3h   = take((size_t)NROWS * 512 * 2);
    const size_t o_m3l   = take((size_t)NROWS * 512 * 2);
    const size_t o_m4h   = take((size_t)NROWS * 2048 * 2);
    const size_t o_m4l   = take((size_t)NROWS * 2048 * 2);
    const size_t o_m5h   = take((size_t)NROWS * 64 * 2);
    const size_t o_m5l   = take((size_t)NROWS * 64 * 2);
    const size_t o_r4h   = take((size_t)NROWS * 64 * 2);
    const size_t o_r4l   = take((size_t)NROWS * 64 * 2);
    const size_t o_h4    = take((size_t)NROWS * 64 * 4);
    const size_t o_h5    = take((size_t)NROWS * 16 * 4);
    // transposed split weights (rows rounded up to 128)
    const size_t o_e1wt  = take((size_t)2 * 512 * 1024 * 2);
    const size_t o_e2wt  = take((size_t)2 * 512 * 512 * 2);
    const size_t o_e3wt  = take((size_t)2 * 2048 * 512 * 2);
    const size_t o_zwt   = take((size_t)2 * 128 * 2048 * 2);
    const size_t o_g1t   = take((size_t)2 * 512 * 1024 * 2);
    const size_t o_g2t   = take((size_t)2 * 512 * 512 * 2);
    const size_t o_g3t   = take((size_t)2 * 2048 * 512 * 2);
    const size_t o_g4t   = take((size_t)2 * 128 * 2048 * 2);
    const size_t o_g5t   = take((size_t)2 * 128 * 64 * 2);
    const size_t o_fcwt  = take((size_t)2 * 1024 * 64 * 2);
    const size_t need_mfma = cur;

    char* wsb = (char*)d_ws;

    if (ws_size >= need_mfma) {
        // ===================== split-bf16 MFMA path =====================
        us* adjh = (us*)(wsb + o_adjh); us* adjl = (us*)(wsb + o_adjl);
        us* xh   = (us*)(wsb + o_xh);   us* xl   = (us*)(wsb + o_xl);
        us* t1h  = (us*)(wsb + o_t1h);  us* t1l  = (us*)(wsb + o_t1l);
        us* t2h  = (us*)(wsb + o_t2h);  us* t2l  = (us*)(wsb + o_t2l);
        us* t3h  = (us*)(wsb + o_t3h);  us* t3l  = (us*)(wsb + o_t3l);
        us* tsh  = (us*)(wsb + o_tsh);  us* tsl  = (us*)(wsb + o_tsl);
        us* m2h  = (us*)(wsb + o_m2h);  us* m2l  = (us*)(wsb + o_m2l);
        us* m3h  = (us*)(wsb + o_m3h);  us* m3l  = (us*)(wsb + o_m3l);
        us* m4h  = (us*)(wsb + o_m4h);  us* m4l  = (us*)(wsb + o_m4l);
        us* m5h  = (us*)(wsb + o_m5h);  us* m5l  = (us*)(wsb + o_m5l);
        us* r4h  = (us*)(wsb + o_r4h);  us* r4l  = (us*)(wsb + o_r4l);
        float* h4 = (float*)(wsb + o_h4);
        float* h5 = (float*)(wsb + o_h5);
        us* e1wt = (us*)(wsb + o_e1wt); us* e2wt = (us*)(wsb + o_e2wt);
        us* e3wt = (us*)(wsb + o_e3wt); us* zwt  = (us*)(wsb + o_zwt);
        us* g1t  = (us*)(wsb + o_g1t);  us* g2t  = (us*)(wsb + o_g2t);
        us* g3t  = (us*)(wsb + o_g3t);  us* g4t  = (us*)(wsb + o_g4t);
        us* g5t  = (us*)(wsb + o_g5t);  us* fcwt = (us*)(wsb + o_fcwt);

        // converts
        split_rm_kernel<<<2048, 256, 0, stream>>>(adj, adjh, adjl, NROWS, NROWS, ADJ_KP);
        split_rm_kernel<<<1024, 256, 0, stream>>>(x, xh, xl, NROWS, 1024, 1024);
        zpad_kernel<<<(2048*16 + EL-1)/EL, EL, 0, stream>>>(tsh, tsl);
        auto wt = [&](const float* w, us* th, us* tl, int K, int N) {
            split_wt_kernel<<<(N*K + EL-1)/EL, EL, 0, stream>>>(w, th, tl, K, N);
        };
        wt(e1w, e1wt, e1wt + (size_t)512*1024, 1024, 512);
        wt(e2w, e2wt, e2wt + (size_t)512*512,  512,  512);
        wt(e3w, e3wt, e3wt + (size_t)2048*512, 512,  2048);
        wt(zw,  zwt,  zwt  + (size_t)128*2048, 2048, 64);
        wt(g1,  g1t,  g1t  + (size_t)512*1024, 1024, 512);
        wt(g2,  g2t,  g2t  + (size_t)512*512,  512,  512);
        wt(g3,  g3t,  g3t  + (size_t)2048*512, 512,  2048);
        wt(g4,  g4t,  g4t  + (size_t)128*2048, 2048, 64);
        wt(g5,  g5t,  g5t  + (size_t)128*64,   64,   16);
        wt(fcw, fcwt, fcwt + (size_t)1024*64,  64,   1024);
        us* e1wtl = e1wt + (size_t)512*1024;  us* e2wtl = e2wt + (size_t)512*512;
        us* e3wtl = e3wt + (size_t)2048*512;  us* zwtl  = zwt  + (size_t)128*2048;
        us* g1tl  = g1t  + (size_t)512*1024;  us* g2tl  = g2t  + (size_t)512*512;
        us* g3tl  = g3t  + (size_t)2048*512;  us* g4tl  = g4t  + (size_t)128*2048;
        us* g5tl  = g5t  + (size_t)128*64;    us* fcwtl = fcwt + (size_t)1024*64;

        // AE encoder (split outputs for next-GEMM A and for the MIX epilogues)
        gemm_split(xh, xl, e1wt, e1wtl, NROWS, 512, 1024, e1b, F_BIAS|F_RELU|F_OUTRM,
                   nullptr, t1h, t1l, 0, nullptr, nullptr, stream);
        gemm_split(t1h, t1l, e2wt, e2wtl, NROWS, 512, 512, e2b, F_BIAS|F_RELU|F_OUTRM,
                   nullptr, t2h, t2l, 0, nullptr, nullptr, stream);
        gemm_split(t2h, t2l, e3wt, e3wtl, NROWS, 2048, 512, e3b, F_BIAS|F_RELU|F_OUTRM,
                   nullptr, t3h, t3l, 0, nullptr, nullptr, stream);
        gemm_split(t3h, t3l, zwt, zwtl, NROWS, 64, 2048, zb, F_BIAS|F_OUTF32,
                   zout, nullptr, nullptr, 0, nullptr, nullptr, stream);

        // GNN1
        gemm_split(xh, xl, g1t, g1tl, NROWS, 512, 1024, nullptr, F_OUTT,
                   nullptr, tsh, tsl, ADJ_KP, nullptr, nullptr, stream);
        gemm_split(adjh, adjl, tsh, tsl, NROWS, 512, ADJ_KP, nullptr, F_RELU|F_MIX|F_OUTRM,
                   nullptr, m2h, m2l, 0, t1h, t1l, stream);
        // GNN2
        gemm_split(m2h, m2l, g2t, g2tl, NROWS, 512, 512, nullptr, F_OUTT,
                   nullptr, tsh, tsl, ADJ_KP, nullptr, nullptr, stream);
        gemm_split(adjh, adjl, tsh, tsl, NROWS, 512, ADJ_KP, nullptr, F_RELU|F_MIX|F_OUTRM,
                   nullptr, m3h, m3l, 0, t2h, t2l, stream);
        // GNN3
        gemm_split(m3h, m3l, g3t, g3tl, NROWS, 2048, 512, nullptr, F_OUTT,
                   nullptr, tsh, tsl, ADJ_KP, nullptr, nullptr, stream);
        gemm_split(adjh, adjl, tsh, tsl, NROWS, 2048, ADJ_KP, nullptr, F_RELU|F_MIX|F_OUTRM,
                   nullptr, m4h, m4l, 0, t3h, t3l, stream);
        // GNN4 (no relu on h4)
        gemm_split(m4h, m4l, g4t, g4tl, NROWS, 64, 2048, nullptr, F_OUTT,
                   nullptr, tsh, tsl, ADJ_KP, nullptr, nullptr, stream);
        gemm_split(adjh, adjl, tsh, tsl, NROWS, 64, ADJ_KP, nullptr, F_OUTF32,
                   h4, nullptr, nullptr, 0, nullptr, nullptr, stream);
        // GNN5
        relu_mix_split_kernel<<<(NROWS*64 + EL-1)/EL, EL, 0, stream>>>(h4, zout, r4h, r4l, m5h, m5l, NROWS*64);
        gemm_split(m5h, m5l, g5t, g5tl, NROWS, 16, 64, nullptr, F_OUTT,
                   nullptr, tsh, tsl, ADJ_KP, nullptr, nullptr, stream);
        gemm_split(adjh, adjl, tsh, tsl, NROWS, 16, ADJ_KP, nullptr, F_OUTF32,
                   h5, nullptr, nullptr, 0, nullptr, nullptr, stream);

        // outputs
        softmax16_kernel<<<(NROWS + EL-1)/EL, EL, 0, stream>>>(h5, pred, NROWS);
        gemm_split(r4h, r4l, fcwt, fcwtl, NROWS, 1024, 64, fcb, F_BIAS|F_RELU|F_OUTF32,
                   x_bar, nullptr, nullptr, 0, nullptr, nullptr, stream);
        qdist_kernel<<<(NROWS + EL-1)/EL, EL, 0, stream>>>(h4, cl, qout, NROWS);
        return;
    }

    // ===================== fp32 fallback path =====================
    size_t fcur = 0;
    auto ftake = [&](size_t b) { void* p = wsb + fcur; fcur += (b + 255) & ~(size_t)255; return p; };
    float* tra1 = (float*)ftake((size_t)NROWS *  512 * 4);
    float* tra2 = (float*)ftake((size_t)NROWS *  512 * 4);
    float* tra3 = (float*)ftake((size_t)NROWS * 2048 * 4);
    float* tbuf = (float*)ftake((size_t)NROWS * 2048 * 4);
    float* hbuf = (float*)ftake((size_t)NROWS * 2048 * 4);
    float* mbuf = (float*)ftake((size_t)NROWS * 2048 * 4);
    float* h4   = (float*)ftake((size_t)NROWS *   64 * 4);
    float* r4   = (float*)ftake((size_t)NROWS *   64 * 4);
    float* h5   = (float*)ftake((size_t)NROWS *   16 * 4);
    if (ws_size < fcur) return;   // nothing safe to do

    gemm128(x,    e1w, e1b, tra1, NROWS,  512, 1024, 1, stream);
    gemm128(tra1, e2w, e2b, tra2, NROWS,  512,  512, 1, stream);
    gemm128(tra2, e3w, e3b, tra3, NROWS, 2048,  512, 1, stream);
    gemm64 (tra3, zw,  zb,  zout, NROWS,   64, 2048, 0, stream);

    gemm128(x,   g1, nullptr, tbuf, NROWS, 512, 1024, 0, stream);
    gemm128(adj, tbuf, nullptr, hbuf, NROWS, 512, NROWS, 1, stream);

    mix_kernel<<<(NROWS*512 + EL-1)/EL, EL, 0, stream>>>(hbuf, tra1, mbuf, NROWS*512);
    gemm128(mbuf, g2, nullptr, tbuf, NROWS, 512, 512, 0, stream);
    gemm128(adj,  tbuf, nullptr, hbuf, NROWS, 512, NROWS, 1, stream);

    mix_kernel<<<(NROWS*512 + EL-1)/EL, EL, 0, stream>>>(hbuf, tra2, mbuf, NROWS*512);
    gemm128(mbuf, g3, nullptr, tbuf, NROWS, 2048, 512, 0, stream);
    gemm128(adj,  tbuf, nullptr, hbuf, NROWS, 2048, NROWS, 1, stream);

    mix_kernel<<<(NROWS*2048 + EL-1)/EL, EL, 0, stream>>>(hbuf, tra3, mbuf, NROWS*2048);
    gemm64(mbuf, g4, nullptr, tbuf, NROWS, 64, 2048, 0, stream);
    gemm64(adj,  tbuf, nullptr, h4,   NROWS, 64, NROWS, 0, stream);

    relu_mix_kernel<<<(NROWS*64 + EL-1)/EL, EL, 0, stream>>>(h4, zout, r4, mbuf, NROWS*64);
    gemm64(mbuf, g5, nullptr, tbuf, NROWS, 16, 64, 0, stream);
    gemm64(adj,  tbuf, nullptr, h5,  NROWS, 16, NROWS, 0, stream);

    softmax16_kernel<<<(NROWS + EL-1)/EL, EL, 0, stream>>>(h5, pred, NROWS);
    gemm128(r4, fcw, fcb, x_bar, NROWS, 1024, 64, 1, stream);
    qdist_kernel<<<(NROWS + EL-1)/EL, EL, 0, stream>>>(h4, cl, qout, NROWS);
}

// Round 5
// 2990.292 us; speedup vs baseline: 1.6715x; 1.6715x over previous
//
#include <hip/hip_runtime.h>

// SDCN forward on MI355X — Round 5 (byte-identical resubmit of R3/R4; both
// benches were GPU-acquisition timeouts, never executed).
//  * adj GEMMs: plain bf16 MFMA (1 mfma/frag) — adj is an averaging operator,
//    rounding noise is averaged down (~2e-5 abs); adj stored hi-only (200MB).
//  * encoder/transform/fc1 GEMMs: split-bf16 (3 mfma/frag) for accuracy.
//  * all GEMMs: global_load_lds width-16 staging, linear LDS (m151: +35%).
//  * adj GEMMs with N<=64: split-K x8 + fp32 atomics (was 79-block latency bound).
// AE decoder is dead code — skipped.

#define NROWS   10000
#define ADJ_KP  10016
#define SIGMA_F 0.3f

typedef short s8v __attribute__((ext_vector_type(8)));
typedef float f4v __attribute__((ext_vector_type(4)));
typedef unsigned short us;
typedef unsigned int u32;

#define F_RELU   1
#define F_BIAS   2
#define F_OUTF32 4
#define F_OUTRM  8
#define F_OUTT   16
#define F_MIX    32
#define F_ATOMIC 64

__device__ __forceinline__ us f2bf(float f) {
    union { float f; u32 u; } c; c.f = f;
    u32 r = c.u + 0x7fffu + ((c.u >> 16) & 1u);
    return (us)(r >> 16);
}
__device__ __forceinline__ float bf2f(us h) {
    union { u32 u; float f; } c; c.u = ((u32)h) << 16;
    return c.f;
}
__device__ __forceinline__ void split2(float f, us& h, us& l) {
    h = f2bf(f);
    l = f2bf(f - bf2f(h));
}

// async global->LDS, 16B per lane; lds dest is wave-uniform (HW adds lane*16)
__device__ __forceinline__ void async16(void* lds, const void* gp) {
    __builtin_amdgcn_global_load_lds(
        (const __attribute__((address_space(1))) u32*)gp,
        (__attribute__((address_space(3))) u32*)lds, 16, 0, 0);
}

// ---------------------------------------------------------------------------
// Split-bf16 GEMM (3 mfma/frag): C = act(A@B + bias). A row-major split pair,
// B transposed split pair Bt[n][k]. 128x128 tile, BK=32, 4 waves.
// global_load_lds staging, linear LDS (32KB: Ah|Al|Bh|Bl 8KB each).
// ---------------------------------------------------------------------------
__global__ __launch_bounds__(256)
void gemm_split_kernel(const us* __restrict__ Ah, const us* __restrict__ Al,
                       const us* __restrict__ Bh, const us* __restrict__ Bl,
                       int M, int N, int Kp, int gx,
                       const float* __restrict__ bias, int flags,
                       float* __restrict__ Cf,
                       us* __restrict__ Ch, us* __restrict__ Cl, int ldct,
                       const us* __restrict__ Mixh, const us* __restrict__ Mixl)
{
    __shared__ char ldsb[32768];
    const int tid  = threadIdx.x;
    const int lane = tid & 63;
    const int wid  = tid >> 6;
    const int wr   = wid >> 1;
    const int wc   = wid & 1;

    const int nwg = gridDim.x;
    const int q8 = nwg >> 3, r8 = nwg & 7;
    const int xcd = blockIdx.x & 7, sidx = blockIdx.x >> 3;
    const int wg = (xcd < r8 ? xcd * (q8 + 1) : r8 * (q8 + 1) + (xcd - r8) * q8) + sidx;
    const int bx = wg % gx, by = wg / gx;
    const long row0 = (long)by * 128;
    const long col0 = (long)bx * 128;

    // wave w stages tile w (Ah|Al|Bh|Bl), 8 chunks of 1KB
    const us* sbase = (wid == 0) ? Ah : (wid == 1) ? Al : (wid == 2) ? Bh : Bl;
    const int ldsoff = wid * 8192;
    long gb[8];
    #pragma unroll
    for (int c = 0; c < 8; ++c) {
        int r = c * 16 + (lane >> 2);
        long gr;
        if (wid < 2) { long t = row0 + r; gr = (t < M) ? t : (long)(M - 1); }
        else         { gr = col0 + r; }
        gb[c] = gr * (long)Kp + (lane & 3) * 8;
    }

    f4v acc[4][4];
    #pragma unroll
    for (int i = 0; i < 4; ++i)
        #pragma unroll
        for (int j = 0; j < 4; ++j) acc[i][j] = (f4v){0.f, 0.f, 0.f, 0.f};

    const int fr = lane & 15, c16 = lane >> 4;
    const int nsteps = Kp >> 5;

    for (int s = 0; s < nsteps; ++s) {
        const long ko = (long)s * 32;
        #pragma unroll
        for (int c = 0; c < 8; ++c)
            async16(ldsb + ldsoff + c * 1024, sbase + gb[c] + ko);
        __syncthreads();   // drains vmcnt before barrier -> LDS ready
        s8v ahf[4], alf[4];
        #pragma unroll
        for (int i = 0; i < 4; ++i) {
            int bo = (wr * 64 + i * 16 + fr) * 64 + c16 * 16;
            ahf[i] = *(const s8v*)(ldsb + bo);
            alf[i] = *(const s8v*)(ldsb + 8192 + bo);
        }
        #pragma unroll
        for (int j = 0; j < 4; ++j) {
            int bo = (wc * 64 + j * 16 + fr) * 64 + c16 * 16;
            s8v bhf = *(const s8v*)(ldsb + 16384 + bo);
            s8v blf = *(const s8v*)(ldsb + 24576 + bo);
            #pragma unroll
            for (int i = 0; i < 4; ++i) {
                acc[i][j] = __builtin_amdgcn_mfma_f32_16x16x32_bf16(ahf[i], bhf, acc[i][j], 0, 0, 0);
                acc[i][j] = __builtin_amdgcn_mfma_f32_16x16x32_bf16(alf[i], bhf, acc[i][j], 0, 0, 0);
                acc[i][j] = __builtin_amdgcn_mfma_f32_16x16x32_bf16(ahf[i], blf, acc[i][j], 0, 0, 0);
            }
        }
        __syncthreads();
    }

    // epilogue: C/D layout col=lane&15, row=(lane>>4)*4+reg (verified R2)
    #pragma unroll
    for (int i = 0; i < 4; ++i) {
        #pragma unroll
        for (int rg = 0; rg < 4; ++rg) {
            long gm = row0 + wr * 64 + i * 16 + c16 * 4 + rg;
            if (gm >= M) continue;
            #pragma unroll
            for (int j = 0; j < 4; ++j) {
                long gn = col0 + wc * 64 + j * 16 + fr;
                if (gn >= N) continue;
                float v = acc[i][j][rg];
                if (flags & F_BIAS) v += bias[gn];
                if (flags & F_RELU) v = fmaxf(v, 0.f);
                if (flags & F_MIX)
                    v = (1.f - SIGMA_F) * v +
                        SIGMA_F * (bf2f(Mixh[gm * (long)N + gn]) + bf2f(Mixl[gm * (long)N + gn]));
                if (flags & F_OUTF32) Cf[gm * (long)N + gn] = v;
                if (flags & F_OUTRM) { us h, l; split2(v, h, l);
                    Ch[gm * (long)N + gn] = h; Cl[gm * (long)N + gn] = l; }
                if (flags & F_OUTT)  Ch[gn * (long)ldct + gm] = f2bf(v);  // hi only
            }
        }
    }
}

// ---------------------------------------------------------------------------
// Plain bf16 GEMM (1 mfma/frag) for adj GEMMs. A=adj hi, B=t-slot hi (Bt[n][k]).
// 128x128 tile, BK=32, LDS 16KB (A|B 8KB). Optional split-K (kchunks>1) with
// fp32 atomicAdd epilogue (Cf must be pre-zeroed).
// ---------------------------------------------------------------------------
__global__ __launch_bounds__(256)
void gemm_bf16_kernel(const us* __restrict__ Ah, const us* __restrict__ Bh,
                      int M, int N, int Kp, int gx, int kchunks, int ksteps,
                      int flags, float* __restrict__ Cf,
                      us* __restrict__ Ch, us* __restrict__ Cl,
                      const us* __restrict__ Mixh, const us* __restrict__ Mixl)
{
    __shared__ char ldsb[16384];
    const int tid  = threadIdx.x;
    const int lane = tid & 63;
    const int wid  = tid >> 6;
    const int wr   = wid >> 1;
    const int wc   = wid & 1;

    int wg2d, chunk;
    if (kchunks > 1) {
        chunk = blockIdx.x % kchunks;
        wg2d  = blockIdx.x / kchunks;
    } else {
        const int nwg = gridDim.x;
        const int q8 = nwg >> 3, r8 = nwg & 7;
        const int xcd = blockIdx.x & 7, sidx = blockIdx.x >> 3;
        wg2d = (xcd < r8 ? xcd * (q8 + 1) : r8 * (q8 + 1) + (xcd - r8) * q8) + sidx;
        chunk = 0;
    }
    const int bx = wg2d % gx, by = wg2d / gx;
    const long row0 = (long)by * 128;
    const long col0 = (long)bx * 128;

    // waves 0,1 stage A halves; waves 2,3 stage B halves; 4 chunks of 1KB each
    const us* sbase = (wid < 2) ? Ah : Bh;
    const int half  = wid & 1;
    const int ldsoff = (wid < 2 ? 0 : 8192) + half * 4096;
    long gb[4];
    #pragma unroll
    for (int c = 0; c < 4; ++c) {
        int r = half * 64 + c * 16 + (lane >> 2);
        long gr;
        if (wid < 2) { long t = row0 + r; gr = (t < M) ? t : (long)(M - 1); }
        else         { gr = col0 + r; }
        gb[c] = gr * (long)Kp + (lane & 3) * 8;
    }

    f4v acc[4][4];
    #pragma unroll
    for (int i = 0; i < 4; ++i)
        #pragma unroll
        for (int j = 0; j < 4; ++j) acc[i][j] = (f4v){0.f, 0.f, 0.f, 0.f};

    const int fr = lane & 15, c16 = lane >> 4;
    const int smax = Kp >> 5;
    const int s0 = chunk * ksteps;
    int s1 = s0 + ksteps; if (s1 > smax) s1 = smax;

    for (int s = s0; s < s1; ++s) {
        const long ko = (long)s * 32;
        #pragma unroll
        for (int c = 0; c < 4; ++c)
            async16(ldsb + ldsoff + c * 1024, sbase + gb[c] + ko);
        __syncthreads();
        s8v af[4];
        #pragma unroll
        for (int i = 0; i < 4; ++i)
            af[i] = *(const s8v*)(ldsb + (wr * 64 + i * 16 + fr) * 64 + c16 * 16);
        #pragma unroll
        for (int j = 0; j < 4; ++j) {
            s8v bf = *(const s8v*)(ldsb + 8192 + (wc * 64 + j * 16 + fr) * 64 + c16 * 16);
            #pragma unroll
            for (int i = 0; i < 4; ++i)
                acc[i][j] = __builtin_amdgcn_mfma_f32_16x16x32_bf16(af[i], bf, acc[i][j], 0, 0, 0);
        }
        __syncthreads();
    }

    #pragma unroll
    for (int i = 0; i < 4; ++i) {
        #pragma unroll
        for (int rg = 0; rg < 4; ++rg) {
            long gm = row0 + wr * 64 + i * 16 + c16 * 4 + rg;
            if (gm >= M) continue;
            #pragma unroll
            for (int j = 0; j < 4; ++j) {
                long gn = col0 + wc * 64 + j * 16 + fr;
                if (gn >= N) continue;
                float v = acc[i][j][rg];
                if (flags & F_ATOMIC) { atomicAdd(Cf + gm * (long)N + gn, v); continue; }
                if (flags & F_RELU) v = fmaxf(v, 0.f);
                if (flags & F_MIX)
                    v = (1.f - SIGMA_F) * v +
                        SIGMA_F * (bf2f(Mixh[gm * (long)N + gn]) + bf2f(Mixl[gm * (long)N + gn]));
                if (flags & F_OUTF32) Cf[gm * (long)N + gn] = v;
                if (flags & F_OUTRM) { us h, l; split2(v, h, l);
                    Ch[gm * (long)N + gn] = h; Cl[gm * (long)N + gn] = l; }
            }
        }
    }
}

// ---------------------------------------------------------------------------
// converts / fused small ops
// ---------------------------------------------------------------------------
__global__ void split_rm_kernel(const float* __restrict__ src, us* __restrict__ h,
                                us* __restrict__ l, long M, long K, long Kp)
{
    long q = Kp >> 2, total = M * q;
    for (long t = (long)blockIdx.x * blockDim.x + threadIdx.x; t < total;
         t += (long)gridDim.x * blockDim.x) {
        long row = t / q, k4 = (t - row * q) << 2;
        us hh[4], ll[4];
        if (k4 < K) {
            const float* p = src + row * K + k4;
            #pragma unroll
            for (int e = 0; e < 4; ++e) split2(p[e], hh[e], ll[e]);
        } else {
            #pragma unroll
            for (int e = 0; e < 4; ++e) { hh[e] = 0; ll[e] = 0; }
        }
        long o = row * Kp + k4;
        *(ushort4*)(h + o) = make_ushort4(hh[0], hh[1], hh[2], hh[3]);
        *(ushort4*)(l + o) = make_ushort4(ll[0], ll[1], ll[2], ll[3]);
    }
}

// hi-only convert (adj)
__global__ void tobf_rm_kernel(const float* __restrict__ src, us* __restrict__ h,
                               long M, long K, long Kp)
{
    long q = Kp >> 2, total = M * q;
    for (long t = (long)blockIdx.x * blockDim.x + threadIdx.x; t < total;
         t += (long)gridDim.x * blockDim.x) {
        long row = t / q, k4 = (t - row * q) << 2;
        us hh[4];
        if (k4 < K) {
            const float* p = src + row * K + k4;
            #pragma unroll
            for (int e = 0; e < 4; ++e) hh[e] = f2bf(p[e]);
        } else {
            #pragma unroll
            for (int e = 0; e < 4; ++e) hh[e] = 0;
        }
        *(ushort4*)(h + row * Kp + k4) = make_ushort4(hh[0], hh[1], hh[2], hh[3]);
    }
}

__global__ void split_wt_kernel(const float* __restrict__ wsrc, us* __restrict__ th,
                                us* __restrict__ tl, int K, int N)
{
    int idx = blockIdx.x * blockDim.x + threadIdx.x;
    if (idx >= N * K) return;
    int n = idx / K, k = idx - n * K;
    us h, l;
    split2(wsrc[(long)k * N + n], h, l);
    th[(long)n * K + k] = h;
    tl[(long)n * K + k] = l;
}

__global__ void zpad_kernel(us* __restrict__ th)
{
    int idx = blockIdx.x * blockDim.x + threadIdx.x;
    if (idx >= 2048 * 16) return;
    int n = idx >> 4, k = 10000 + (idx & 15);
    th[(long)n * ADJ_KP + k] = 0;
}

__global__ void zero_f32_kernel(float* __restrict__ p, long n)
{
    for (long i = (long)blockIdx.x * blockDim.x + threadIdx.x; i < n;
         i += (long)gridDim.x * blockDim.x) p[i] = 0.f;
}

__global__ void relu_mix_split_kernel(const float* __restrict__ h4, const float* __restrict__ z,
                                      us* __restrict__ r4h, us* __restrict__ r4l,
                                      us* __restrict__ m5h, us* __restrict__ m5l, int n)
{
    int i = blockIdx.x * blockDim.x + threadIdx.x;
    if (i >= n) return;
    float r = fmaxf(h4[i], 0.f);
    us h, l;
    split2(r, h, l); r4h[i] = h; r4l[i] = l;
    float m = (1.f - SIGMA_F) * r + SIGMA_F * z[i];
    split2(m, h, l); m5h[i] = h; m5l[i] = l;
}

__global__ void softmax16_kernel(const float* __restrict__ hv, float* __restrict__ out, int M)
{
    int r = blockIdx.x * blockDim.x + threadIdx.x;
    if (r >= M) return;
    float v[16], mx = -1e30f;
    #pragma unroll
    for (int j = 0; j < 16; ++j) { v[j] = hv[r * 16 + j]; mx = fmaxf(mx, v[j]); }
    float s = 0.f;
    #pragma unroll
    for (int j = 0; j < 16; ++j) { v[j] = __expf(v[j] - mx); s += v[j]; }
    float inv = 1.f / s;
    #pragma unroll
    for (int j = 0; j < 16; ++j) out[r * 16 + j] = v[j] * inv;
}

__global__ void qdist_kernel(const float* __restrict__ h4, const float* __restrict__ cluster,
                             float* __restrict__ q, int M)
{
    int r = blockIdx.x * blockDim.x + threadIdx.x;
    if (r >= M) return;
    float d2[16];
    #pragma unroll
    for (int k = 0; k < 16; ++k) d2[k] = 0.f;
    for (int d = 0; d < 64; ++d) {
        float hv = h4[r * 64 + d];
        #pragma unroll
        for (int k = 0; k < 16; ++k) {
            float df = hv - cluster[k * 64 + d];
            d2[k] = fmaf(df, df, d2[k]);
        }
    }
    float s = 0.f, qq[16];
    #pragma unroll
    for (int k = 0; k < 16; ++k) { qq[k] = 1.f / (1.f + d2[k]); s += qq[k]; }
    float inv = 1.f / s;
    #pragma unroll
    for (int k = 0; k < 16; ++k) q[r * 16 + k] = qq[k] * inv;
}

// ---------------------------------------------------------------------------
static inline void gemm_split(const us* Ah, const us* Al, const us* Bh, const us* Bl,
                              int M, int N, int Kp, const float* bias, int flags,
                              float* Cf, us* Ch, us* Cl, int ldct,
                              const us* Mixh, const us* Mixl, hipStream_t s)
{
    int gx = (N + 127) / 128, gy = (M + 127) / 128;
    gemm_split_kernel<<<gx * gy, 256, 0, s>>>(Ah, Al, Bh, Bl, M, N, Kp, gx,
                                              bias, flags, Cf, Ch, Cl, ldct, Mixh, Mixl);
}
static inline void gemm_adj(const us* A, const us* B, int M, int N, int kchunks,
                            int flags, float* Cf, us* Ch, us* Cl,
                            const us* Mixh, const us* Mixl, hipStream_t s)
{
    int gx = (N + 127) / 128, gy = (M + 127) / 128;
    int smax = ADJ_KP >> 5;
    int ksteps = (smax + kchunks - 1) / kchunks;
    gemm_bf16_kernel<<<gx * gy * kchunks, 256, 0, s>>>(A, B, M, N, ADJ_KP, gx,
                                                       kchunks, ksteps, flags,
                                                       Cf, Ch, Cl, Mixh, Mixl);
}

extern "C" void kernel_launch(void* const* d_in, const int* in_sizes, int n_in,
                              void* d_out, int out_size, void* d_ws, size_t ws_size,
                              hipStream_t stream)
{
    const float* x    = (const float*)d_in[0];
    const float* adj  = (const float*)d_in[1];
    const float* e1w  = (const float*)d_in[2];   const float* e1b = (const float*)d_in[3];
    const float* e2w  = (const float*)d_in[4];   const float* e2b = (const float*)d_in[5];
    const float* e3w  = (const float*)d_in[6];   const float* e3b = (const float*)d_in[7];
    const float* zw   = (const float*)d_in[8];   const float* zb  = (const float*)d_in[9];
    const float* g1   = (const float*)d_in[18];
    const float* g2   = (const float*)d_in[19];
    const float* g3   = (const float*)d_in[20];
    const float* g4   = (const float*)d_in[21];
    const float* g5   = (const float*)d_in[22];
    const float* fcw  = (const float*)d_in[23];  const float* fcb = (const float*)d_in[24];
    const float* cl   = (const float*)d_in[25];

    float* out   = (float*)d_out;
    float* x_bar = out;
    float* qout  = out + (size_t)NROWS * 1024;
    float* pred  = qout + (size_t)NROWS * 16;
    float* zout  = pred + (size_t)NROWS * 16;

    const int EL = 256;

    // ---------- workspace ----------
    char* wsb = (char*)d_ws;
    size_t cur = 0;
    auto take = [&](size_t b) { void* p = wsb + cur; cur += (b + 255) & ~(size_t)255; return p; };
    us* adjh = (us*)take((size_t)NROWS * ADJ_KP * 2);        // 200 MB, hi only
    us* xh   = (us*)take((size_t)NROWS * 1024 * 2);
    us* xl   = (us*)take((size_t)NROWS * 1024 * 2);
    us* t1h  = (us*)take((size_t)NROWS * 512 * 2);
    us* t1l  = (us*)take((size_t)NROWS * 512 * 2);
    us* t2h  = (us*)take((size_t)NROWS * 512 * 2);
    us* t2l  = (us*)take((size_t)NROWS * 512 * 2);
    us* t3h  = (us*)take((size_t)NROWS * 2048 * 2);
    us* t3l  = (us*)take((size_t)NROWS * 2048 * 2);
    us* tsh  = (us*)take((size_t)2048 * ADJ_KP * 2);         // t-slot, hi only
    us* m2h  = (us*)take((size_t)NROWS * 512 * 2);
    us* m2l  = (us*)take((size_t)NROWS * 512 * 2);
    us* m3h  = (us*)take((size_t)NROWS * 512 * 2);
    us* m3l  = (us*)take((size_t)NROWS * 512 * 2);
    us* m4h  = (us*)take((size_t)NROWS * 2048 * 2);
    us* m4l  = (us*)take((size_t)NROWS * 2048 * 2);
    us* m5h  = (us*)take((size_t)NROWS * 64 * 2);
    us* m5l  = (us*)take((size_t)NROWS * 64 * 2);
    us* r4h  = (us*)take((size_t)NROWS * 64 * 2);
    us* r4l  = (us*)take((size_t)NROWS * 64 * 2);
    float* h4 = (float*)take((size_t)NROWS * 64 * 4);
    float* h5 = (float*)take((size_t)NROWS * 16 * 4);
    us* e1wt = (us*)take((size_t)2 * 512 * 1024 * 2);
    us* e2wt = (us*)take((size_t)2 * 512 * 512 * 2);
    us* e3wt = (us*)take((size_t)2 * 2048 * 512 * 2);
    us* zwt  = (us*)take((size_t)2 * 128 * 2048 * 2);
    us* g1t  = (us*)take((size_t)2 * 512 * 1024 * 2);
    us* g2t  = (us*)take((size_t)2 * 512 * 512 * 2);
    us* g3t  = (us*)take((size_t)2 * 2048 * 512 * 2);
    us* g4t  = (us*)take((size_t)2 * 128 * 2048 * 2);
    us* g5t  = (us*)take((size_t)2 * 128 * 64 * 2);
    us* fcwt = (us*)take((size_t)2 * 1024 * 64 * 2);
    if (ws_size < cur) return;   // should not happen (R2 ran with larger layout)

    us* e1wtl = e1wt + (size_t)512 * 1024;  us* e2wtl = e2wt + (size_t)512 * 512;
    us* e3wtl = e3wt + (size_t)2048 * 512;  us* zwtl  = zwt  + (size_t)128 * 2048;
    us* g1tl  = g1t  + (size_t)512 * 1024;  us* g2tl  = g2t  + (size_t)512 * 512;
    us* g3tl  = g3t  + (size_t)2048 * 512;  us* g4tl  = g4t  + (size_t)128 * 2048;
    us* g5tl  = g5t  + (size_t)128 * 64;    us* fcwtl = fcwt + (size_t)1024 * 64;

    // ---------- converts ----------
    tobf_rm_kernel<<<2048, 256, 0, stream>>>(adj, adjh, NROWS, NROWS, ADJ_KP);
    split_rm_kernel<<<1024, 256, 0, stream>>>(x, xh, xl, NROWS, 1024, 1024);
    zpad_kernel<<<(2048 * 16 + EL - 1) / EL, EL, 0, stream>>>(tsh);
    auto wt = [&](const float* w, us* th, us* tl, int K, int N) {
        split_wt_kernel<<<(N * K + EL - 1) / EL, EL, 0, stream>>>(w, th, tl, K, N);
    };
    wt(e1w, e1wt, e1wtl, 1024, 512);
    wt(e2w, e2wt, e2wtl, 512, 512);
    wt(e3w, e3wt, e3wtl, 512, 2048);
    wt(zw,  zwt,  zwtl,  2048, 64);
    wt(g1,  g1t,  g1tl,  1024, 512);
    wt(g2,  g2t,  g2tl,  512, 512);
    wt(g3,  g3t,  g3tl,  512, 2048);
    wt(g4,  g4t,  g4tl,  2048, 64);
    wt(g5,  g5t,  g5tl,  64, 16);
    wt(fcw, fcwt, fcwtl, 64, 1024);

    // ---------- AE encoder (split-3, accurate: feeds z output & mixes) ----------
    gemm_split(xh, xl, e1wt, e1wtl, NROWS, 512, 1024, e1b, F_BIAS | F_RELU | F_OUTRM,
               nullptr, t1h, t1l, 0, nullptr, nullptr, stream);
    gemm_split(t1h, t1l, e2wt, e2wtl, NROWS, 512, 512, e2b, F_BIAS | F_RELU | F_OUTRM,
               nullptr, t2h, t2l, 0, nullptr, nullptr, stream);
    gemm_split(t2h, t2l, e3wt, e3wtl, NROWS, 2048, 512, e3b, F_BIAS | F_RELU | F_OUTRM,
               nullptr, t3h, t3l, 0, nullptr, nullptr, stream);
    gemm_split(t3h, t3l, zwt, zwtl, NROWS, 64, 2048, zb, F_BIAS | F_OUTF32,
               zout, nullptr, nullptr, 0, nullptr, nullptr, stream);

    // ---------- GNN1 ----------
    gemm_split(xh, xl, g1t, g1tl, NROWS, 512, 1024, nullptr, F_OUTT,
               nullptr, tsh, nullptr, ADJ_KP, nullptr, nullptr, stream);
    gemm_adj(adjh, tsh, NROWS, 512, 1, F_RELU | F_MIX | F_OUTRM,
             nullptr, m2h, m2l, t1h, t1l, stream);
    // ---------- GNN2 ----------
    gemm_split(m2h, m2l, g2t, g2tl, NROWS, 512, 512, nullptr, F_OUTT,
               nullptr, tsh, nullptr, ADJ_KP, nullptr, nullptr, stream);
    gemm_adj(adjh, tsh, NROWS, 512, 1, F_RELU | F_MIX | F_OUTRM,
             nullptr, m3h, m3l, t2h, t2l, stream);
    // ---------- GNN3 ----------
    gemm_split(m3h, m3l, g3t, g3tl, NROWS, 2048, 512, nullptr, F_OUTT,
               nullptr, tsh, nullptr, ADJ_KP, nullptr, nullptr, stream);
    gemm_adj(adjh, tsh, NROWS, 2048, 1, F_RELU | F_MIX | F_OUTRM,
             nullptr, m4h, m4l, t3h, t3l, stream);
    // ---------- GNN4 (no relu on h4) ----------
    gemm_split(m4h, m4l, g4t, g4tl, NROWS, 64, 2048, nullptr, F_OUTT,
               nullptr, tsh, nullptr, ADJ_KP, nullptr, nullptr, stream);
    zero_f32_kernel<<<512, 256, 0, stream>>>(h4, (long)NROWS * 64);
    gemm_adj(adjh, tsh, NROWS, 64, 8, F_ATOMIC, h4, nullptr, nullptr, nullptr, nullptr, stream);
    // ---------- GNN5 ----------
    relu_mix_split_kernel<<<(NROWS * 64 + EL - 1) / EL, EL, 0, stream>>>(
        h4, zout, r4h, r4l, m5h, m5l, NROWS * 64);
    gemm_split(m5h, m5l, g5t, g5tl, NROWS, 16, 64, nullptr, F_OUTT,
               nullptr, tsh, nullptr, ADJ_KP, nullptr, nullptr, stream);
    zero_f32_kernel<<<128, 256, 0, stream>>>(h5, (long)NROWS * 16);
    gemm_adj(adjh, tsh, NROWS, 16, 8, F_ATOMIC, h5, nullptr, nullptr, nullptr, nullptr, stream);

    // ---------- outputs ----------
    softmax16_kernel<<<(NROWS + EL - 1) / EL, EL, 0, stream>>>(h5, pred, NROWS);
    gemm_split(r4h, r4l, fcwt, fcwtl, NROWS, 1024, 64, fcb, F_BIAS | F_RELU | F_OUTF32,
               x_bar, nullptr, nullptr, 0, nullptr, nullptr, stream);
    qdist_kernel<<<(NROWS + EL - 1) / EL, EL, 0, stream>>>(h4, cl, qout, NROWS);
}